// Round 1
// baseline (663.239 us; speedup 1.0000x reference)
//
#include <hip/hip_runtime.h>
#include <hip/hip_bf16.h>

#define NH   32
#define NKV  8
#define HD   128
#define SL   2048
#define HID  4096
#define KVW  1024   // NKV*HD

typedef __attribute__((ext_vector_type(8))) short short8;
typedef __attribute__((ext_vector_type(4))) float f32x4;

static __device__ __forceinline__ unsigned short f2bf(float f){
  union { float f; unsigned int i; } v; v.f = f;
  unsigned int r = v.i + 0x7FFFu + ((v.i >> 16) & 1u);
  return (unsigned short)(r >> 16);
}
static __device__ __forceinline__ float bf2f(unsigned short u){
  union { unsigned int i; float f; } v; v.i = ((unsigned int)u) << 16; return v.f;
}
static __device__ __forceinline__ unsigned int pack2(float lo, float hi){
  return (unsigned int)f2bf(lo) | ((unsigned int)f2bf(hi) << 16);
}

// ---------------- cast fp32 -> bf16, 8 elems/thread ----------------
__global__ void cast_f32_bf16(const float* __restrict__ src, uint4* __restrict__ dst, int n8){
  int stride = gridDim.x * blockDim.x;
  for (int i = blockIdx.x * blockDim.x + threadIdx.x; i < n8; i += stride){
    float4 a = ((const float4*)src)[2*i + 0];
    float4 b = ((const float4*)src)[2*i + 1];
    uint4 o;
    o.x = pack2(a.x, a.y); o.y = pack2(a.z, a.w);
    o.z = pack2(b.x, b.y); o.w = pack2(b.z, b.w);
    dst[i] = o;
  }
}

// ---------------- RoPE cos/sin table: tab[s][f] = (cos, sin) ----------------
__global__ void rope_table_kernel(const int* __restrict__ pos, float2* __restrict__ tab){
  int i = blockIdx.x * blockDim.x + threadIdx.x;
  if (i >= SL * 64) return;
  int s = i >> 6, f = i & 63;
  // inv_freq = theta^(-2f/128); log(10000) = 9.210340371976184
  float inv = expf(-((float)(2 * f) / 128.0f) * 9.210340371976184f);
  float ang = (float)pos[s] * inv;
  float sn, cs;
  sincosf(ang, &sn, &cs);
  tab[i] = make_float2(cs, sn);
}

// ---------------- in-place RoPE on bf16 [s][h*128+d] ----------------
__global__ void rope_apply_kernel(unsigned short* x, const float2* __restrict__ tab, int nheads){
  int i = blockIdx.x * blockDim.x + threadIdx.x;
  int total = SL * nheads * 64;
  if (i >= total) return;
  int f = i & 63;
  int t = i >> 6;
  int h = t % nheads;
  int s = t / nheads;
  float2 cs = tab[s * 64 + f];
  int base = (s * nheads + h) * HD;
  float x1 = bf2f(x[base + f]);
  float x2 = bf2f(x[base + f + 64]);
  x[base + f]      = f2bf(x1 * cs.x - x2 * cs.y);
  x[base + f + 64] = f2bf(x2 * cs.x + x1 * cs.y);
}

// ---------------- bt-GEMM: C[M][N] = A[M][K] * B[N][K]^T (bf16 in) ----------------
// 128x128 tile, BK=32, 4 waves (2x2), each wave 64x64 = 4x4 frags of 16x16x32.
template<bool F32OUT>
__global__ __launch_bounds__(256) void gemm_bt(
  const unsigned short* __restrict__ A,
  const unsigned short* __restrict__ B,
  void* __restrict__ Cp, int M, int N, int K)
{
  // row length 40 elems (80 B): 16B-aligned rows, 2-way bank aliasing (free)
  __shared__ __align__(16) unsigned short As[128 * 40];
  __shared__ __align__(16) unsigned short Bs[128 * 40];
  const int tid = threadIdx.x;
  const int lane = tid & 63, wid = tid >> 6;
  const int g = lane >> 4, c15 = lane & 15;
  const int wr = wid >> 1, wc = wid & 1;
  const int n0 = blockIdx.x * 128, m0 = blockIdx.y * 128;

  f32x4 acc[4][4];
#pragma unroll
  for (int m = 0; m < 4; ++m)
#pragma unroll
    for (int n = 0; n < 4; ++n) acc[m][n] = (f32x4){0.f, 0.f, 0.f, 0.f};

  const int nk = K >> 5;
  for (int kt = 0; kt < nk; ++kt){
    const int k0 = kt * 32;
    __syncthreads();
#pragma unroll
    for (int i = 0; i < 2; ++i){
      int ch = i * 256 + tid;          // 512 chunks of 8 elems
      int row = ch >> 2, co = (ch & 3) * 8;
      *(uint4*)(&As[row * 40 + co]) = *(const uint4*)(&A[(m0 + row) * K + k0 + co]);
      *(uint4*)(&Bs[row * 40 + co]) = *(const uint4*)(&B[(n0 + row) * K + k0 + co]);
    }
    __syncthreads();
    short8 af[4], bfr[4];
#pragma unroll
    for (int m = 0; m < 4; ++m)
      af[m] = *(const short8*)(&As[(wr * 64 + m * 16 + c15) * 40 + g * 8]);
#pragma unroll
    for (int n = 0; n < 4; ++n)
      bfr[n] = *(const short8*)(&Bs[(wc * 64 + n * 16 + c15) * 40 + g * 8]);
#pragma unroll
    for (int m = 0; m < 4; ++m)
#pragma unroll
      for (int n = 0; n < 4; ++n)
        acc[m][n] = __builtin_amdgcn_mfma_f32_16x16x32_bf16(af[m], bfr[n], acc[m][n], 0, 0, 0);
  }

#pragma unroll
  for (int m = 0; m < 4; ++m)
#pragma unroll
    for (int n = 0; n < 4; ++n){
      int row = m0 + wr * 64 + m * 16 + g * 4;
      int col = n0 + wc * 64 + n * 16 + c15;
      f32x4 v = acc[m][n];
      if (F32OUT){
        float* C = (float*)Cp;
#pragma unroll
        for (int r = 0; r < 4; ++r) C[(row + r) * N + col] = v[r];
      } else {
        unsigned short* C = (unsigned short*)Cp;
#pragma unroll
        for (int r = 0; r < 4; ++r) C[(row + r) * N + col] = f2bf(v[r]);
      }
    }
}

// ---------------- V transpose: v[s][kvh*128+d] -> vt[kvh][d][s] ----------------
__global__ void transpose_v_kernel(const unsigned short* __restrict__ v, unsigned short* __restrict__ vt){
  __shared__ unsigned short t[64][65];
  int h  = blockIdx.z;
  int d0 = blockIdx.y * 64;
  int s0 = blockIdx.x * 64;
  int c  = threadIdx.x & 63;
  int r0 = threadIdx.x >> 6;
#pragma unroll
  for (int r = r0; r < 64; r += 4) t[r][c] = v[(s0 + r) * KVW + h * HD + d0 + c];
  __syncthreads();
#pragma unroll
  for (int r = r0; r < 64; r += 4) vt[(h * HD + d0 + r) * SL + s0 + c] = t[c][r];
}

// ---------------- flash attention: causal, GQA 4:1 ----------------
// block = 64 q-rows of one head; 4 waves x 16 rows; KV tile = 64.
__global__ __launch_bounds__(256) void flash_attn_kernel(
  const unsigned short* __restrict__ Q,
  const unsigned short* __restrict__ Kb,
  const unsigned short* __restrict__ Vt,
  unsigned short* __restrict__ O)
{
  __shared__ __align__(16) unsigned short Ks[64 * 136];   // K rows, pad 128->136
  __shared__ __align__(16) unsigned short Vs[128 * 72];   // V^T rows, pad 64->72
  __shared__ __align__(16) unsigned short Ps[64 * 72];    // P per wave, pad 64->72
  const int tid = threadIdx.x, lane = tid & 63, wid = tid >> 6;
  const int g = lane >> 4, c15 = lane & 15;
  const int qb = blockIdx.x, h = blockIdx.y, kvh = h >> 2;
  const int q0 = qb * 64;

  // Q fragments in registers: A[row=c15][k = kk*32 + g*8 + j]
  short8 aq[4];
  {
    int qrow = q0 + wid * 16 + c15;
#pragma unroll
    for (int kk = 0; kk < 4; ++kk)
      aq[kk] = *(const short8*)(&Q[qrow * HID + h * HD + kk * 32 + g * 8]);
  }

  float m_i[4] = {-1e30f, -1e30f, -1e30f, -1e30f};
  float l_i[4] = {0.f, 0.f, 0.f, 0.f};
  f32x4 oacc[8];
#pragma unroll
  for (int df = 0; df < 8; ++df) oacc[df] = (f32x4){0.f, 0.f, 0.f, 0.f};

  const float scale = 0.08838834764831845f;  // 1/sqrt(128)
  const int nt = qb + 1;
  for (int kt = 0; kt < nt; ++kt){
    // stage K tile (64x128) and V^T tile (128x64)
#pragma unroll
    for (int i = 0; i < 4; ++i){
      int ch = i * 256 + tid;
      { int r = ch >> 4, co = (ch & 15) * 8;
        *(uint4*)(&Ks[r * 136 + co]) = *(const uint4*)(&Kb[(kt * 64 + r) * KVW + kvh * HD + co]); }
      { int r = ch >> 3, co = (ch & 7) * 8;
        *(uint4*)(&Vs[r * 72 + co]) = *(const uint4*)(&Vt[(kvh * HD + r) * SL + kt * 64 + co]); }
    }
    __syncthreads();

    // S = Q K^T
    f32x4 sc[4];
#pragma unroll
    for (int f = 0; f < 4; ++f){
      sc[f] = (f32x4){0.f, 0.f, 0.f, 0.f};
#pragma unroll
      for (int kk = 0; kk < 4; ++kk){
        short8 bk = *(const short8*)(&Ks[(f * 16 + c15) * 136 + kk * 32 + g * 8]);
        sc[f] = __builtin_amdgcn_mfma_f32_16x16x32_bf16(aq[kk], bk, sc[f], 0, 0, 0);
      }
    }

    // mask + online softmax (rows = g*4+r, cols = f*16+c15)
    float p[4][4];
#pragma unroll
    for (int f = 0; f < 4; ++f){
      int col = kt * 64 + f * 16 + c15;
#pragma unroll
      for (int r = 0; r < 4; ++r){
        int row = q0 + wid * 16 + g * 4 + r;
        float s = sc[f][r] * scale;
        p[f][r] = (col <= row) ? s : -1e30f;
      }
    }
#pragma unroll
    for (int r = 0; r < 4; ++r){
      float mx = fmaxf(fmaxf(p[0][r], p[1][r]), fmaxf(p[2][r], p[3][r]));
#pragma unroll
      for (int off = 1; off < 16; off <<= 1) mx = fmaxf(mx, __shfl_xor(mx, off, 64));
      float mnew = fmaxf(m_i[r], mx);
      float cf = __expf(m_i[r] - mnew);
      float rs = 0.f;
#pragma unroll
      for (int f = 0; f < 4; ++f){ float e = __expf(p[f][r] - mnew); p[f][r] = e; rs += e; }
#pragma unroll
      for (int off = 1; off < 16; off <<= 1) rs += __shfl_xor(rs, off, 64);
      l_i[r] = l_i[r] * cf + rs;
      m_i[r] = mnew;
#pragma unroll
      for (int df = 0; df < 8; ++df) oacc[df][r] *= cf;
    }

    // P -> LDS (bf16) as PV A-operand
#pragma unroll
    for (int f = 0; f < 4; ++f)
#pragma unroll
      for (int r = 0; r < 4; ++r)
        Ps[(wid * 16 + g * 4 + r) * 72 + f * 16 + c15] = f2bf(p[f][r]);
    __syncthreads();

    // O += P V   (B[k][col=d] = Vt[d][k], contiguous)
#pragma unroll
    for (int kk = 0; kk < 2; ++kk){
      short8 pa = *(const short8*)(&Ps[(wid * 16 + c15) * 72 + kk * 32 + g * 8]);
#pragma unroll
      for (int df = 0; df < 8; ++df){
        short8 bv = *(const short8*)(&Vs[(df * 16 + c15) * 72 + kk * 32 + g * 8]);
        oacc[df] = __builtin_amdgcn_mfma_f32_16x16x32_bf16(pa, bv, oacc[df], 0, 0, 0);
      }
    }
    __syncthreads();
  }

#pragma unroll
  for (int df = 0; df < 8; ++df)
#pragma unroll
    for (int r = 0; r < 4; ++r){
      int row = q0 + wid * 16 + g * 4 + r;
      O[row * HID + h * HD + df * 16 + c15] = f2bf(oacc[df][r] / l_i[r]);
    }
}

extern "C" void kernel_launch(void* const* d_in, const int* in_sizes, int n_in,
                              void* d_out, int out_size, void* d_ws, size_t ws_size,
                              hipStream_t stream)
{
  const float* hs  = (const float*)d_in[0];
  const float* qw  = (const float*)d_in[1];
  const float* kw  = (const float*)d_in[2];
  const float* vw  = (const float*)d_in[3];
  const float* ow  = (const float*)d_in[4];
  const int*   pos = (const int*)d_in[5];

  char* w = (char*)d_ws;
  auto alloc = [&](size_t bytes){ char* p = w; w += (bytes + 255) & ~(size_t)255; return p; };
  unsigned short* xb  = (unsigned short*)alloc((size_t)SL * HID * 2);
  unsigned short* qwb = (unsigned short*)alloc((size_t)HID * HID * 2);
  unsigned short* kwb = (unsigned short*)alloc((size_t)KVW * HID * 2);
  unsigned short* vwb = (unsigned short*)alloc((size_t)KVW * HID * 2);
  unsigned short* owb = (unsigned short*)alloc((size_t)HID * HID * 2);
  unsigned short* qb  = (unsigned short*)alloc((size_t)SL * HID * 2);
  unsigned short* kb  = (unsigned short*)alloc((size_t)SL * KVW * 2);
  unsigned short* vb  = (unsigned short*)alloc((size_t)SL * KVW * 2);
  unsigned short* vt  = (unsigned short*)alloc((size_t)SL * KVW * 2);
  unsigned short* ab  = (unsigned short*)alloc((size_t)SL * HID * 2);
  float2*         tab = (float2*)alloc((size_t)SL * 64 * sizeof(float2));

  auto cast = [&](const float* s, unsigned short* d, long n){
    int n8 = (int)(n / 8);
    int blocks = (n8 + 255) / 256; if (blocks > 2048) blocks = 2048;
    cast_f32_bf16<<<blocks, 256, 0, stream>>>(s, (uint4*)d, n8);
  };
  cast(hs, xb,  (long)SL * HID);
  cast(qw, qwb, (long)HID * HID);
  cast(kw, kwb, (long)KVW * HID);
  cast(vw, vwb, (long)KVW * HID);
  cast(ow, owb, (long)HID * HID);

  rope_table_kernel<<<(SL * 64 + 255) / 256, 256, 0, stream>>>(pos, tab);

  gemm_bt<false><<<dim3(HID / 128, SL / 128), 256, 0, stream>>>(xb, qwb, qb, SL, HID, HID);
  gemm_bt<false><<<dim3(KVW / 128, SL / 128), 256, 0, stream>>>(xb, kwb, kb, SL, KVW, HID);
  gemm_bt<false><<<dim3(KVW / 128, SL / 128), 256, 0, stream>>>(xb, vwb, vb, SL, KVW, HID);

  rope_apply_kernel<<<(SL * NH  * 64 + 255) / 256, 256, 0, stream>>>(qb, tab, NH);
  rope_apply_kernel<<<(SL * NKV * 64 + 255) / 256, 256, 0, stream>>>(kb, tab, NKV);

  transpose_v_kernel<<<dim3(SL / 64, HD / 64, NKV), 256, 0, stream>>>(vb, vt);

  flash_attn_kernel<<<dim3(SL / 64, NH), 256, 0, stream>>>(qb, kb, vt, ab);

  gemm_bt<true><<<dim3(HID / 128, SL / 128), 256, 0, stream>>>(ab, owb, d_out, SL, HID, HID);
}

// Round 2
// 444.750 us; speedup vs baseline: 1.4913x; 1.4913x over previous
//
#include <hip/hip_runtime.h>
#include <hip/hip_bf16.h>

#define NH   32
#define NKV  8
#define HD   128
#define SL   2048
#define HID  4096
#define KVW  1024   // NKV*HD
#define QKVN 6144   // HID + 2*KVW

typedef __attribute__((ext_vector_type(8))) short short8;
typedef __attribute__((ext_vector_type(4))) float f32x4;

static __device__ __forceinline__ unsigned short f2bf(float f){
  union { float f; unsigned int i; } v; v.f = f;
  unsigned int r = v.i + 0x7FFFu + ((v.i >> 16) & 1u);
  return (unsigned short)(r >> 16);
}
static __device__ __forceinline__ float bf2f(unsigned short u){
  union { unsigned int i; float f; } v; v.i = ((unsigned int)u) << 16; return v.f;
}
static __device__ __forceinline__ unsigned int pack2(float lo, float hi){
  return (unsigned int)f2bf(lo) | ((unsigned int)f2bf(hi) << 16);
}

// async global -> LDS, 16 B per lane. LDS dest is wave-uniform base + lane*16.
static __device__ __forceinline__ void gload_lds16(const void* g, void* l){
  __builtin_amdgcn_global_load_lds(
      (const __attribute__((address_space(1))) void*)g,
      (__attribute__((address_space(3))) void*)l,
      16, 0, 0);
}

// ---------------- cast fp32 -> bf16, 8 elems/thread ----------------
__global__ void cast_f32_bf16(const float* __restrict__ src, uint4* __restrict__ dst, int n8){
  int stride = gridDim.x * blockDim.x;
  for (int i = blockIdx.x * blockDim.x + threadIdx.x; i < n8; i += stride){
    float4 a = ((const float4*)src)[2*i + 0];
    float4 b = ((const float4*)src)[2*i + 1];
    uint4 o;
    o.x = pack2(a.x, a.y); o.y = pack2(a.z, a.w);
    o.z = pack2(b.x, b.y); o.w = pack2(b.z, b.w);
    dst[i] = o;
  }
}

// ---------------- RoPE cos/sin table ----------------
__global__ void rope_table_kernel(const int* __restrict__ pos, float2* __restrict__ tab){
  int i = blockIdx.x * blockDim.x + threadIdx.x;
  if (i >= SL * 64) return;
  int s = i >> 6, f = i & 63;
  float inv = expf(-((float)(2 * f) / 128.0f) * 9.210340371976184f);
  float ang = (float)pos[s] * inv;
  float sn, cs;
  sincosf(ang, &sn, &cs);
  tab[i] = make_float2(cs, sn);
}

// ---------------- in-place RoPE on bf16 [s][stride] ----------------
__global__ void rope_apply_kernel(unsigned short* x, const float2* __restrict__ tab,
                                  int nheads, int rowstride){
  int i = blockIdx.x * blockDim.x + threadIdx.x;
  int total = SL * nheads * 64;
  if (i >= total) return;
  int f = i & 63;
  int t = i >> 6;
  int h = t % nheads;
  int s = t / nheads;
  float2 cs = tab[s * 64 + f];
  size_t base = (size_t)s * rowstride + h * HD;
  float x1 = bf2f(x[base + f]);
  float x2 = bf2f(x[base + f + 64]);
  x[base + f]      = f2bf(x1 * cs.x - x2 * cs.y);
  x[base + f + 64] = f2bf(x2 * cs.x + x1 * cs.y);
}

// ---------------- bt-GEMM (m97 structure): C[M][N] = A[M][K] * B[N][K]^T ----------------
// 128x128 tile, BK=32, 4 waves (2x2), global_load_lds width-16 staging, linear LDS.
template<bool F32OUT>
__global__ __launch_bounds__(256) void gemm_bt(
  const unsigned short* __restrict__ A,
  const unsigned short* __restrict__ B,
  void* __restrict__ Cp, int M, int N, int K)
{
  __shared__ __align__(16) unsigned short As[128 * 32];
  __shared__ __align__(16) unsigned short Bs[128 * 32];
  const int tid = threadIdx.x;
  const int lane = tid & 63, wid = tid >> 6;
  const int g = lane >> 4, c15 = lane & 15;
  const int wr = wid >> 1, wc = wid & 1;

  // bijective XCD swizzle (grid % 8 == 0 for all our launches)
  int nwg = gridDim.x * gridDim.y;
  int lin = blockIdx.y * gridDim.x + blockIdx.x;
  int cpx = nwg >> 3;
  int swz = (lin & 7) * cpx + (lin >> 3);
  const int n0 = (swz % gridDim.x) * 128;
  const int m0 = (swz / gridDim.x) * 128;

  // staging: wave wid covers rows [wid*32, wid*32+32), 2 issues of 16 rows each side
  const int srow = wid * 32 + (lane >> 2);
  const int scol = (lane & 3) * 8;
  const unsigned short* Ag = &A[(size_t)(m0 + srow) * K + scol];
  const unsigned short* Bg = &B[(size_t)(n0 + srow) * K + scol];
  unsigned short* Asl = &As[wid * 1024];   // wave-uniform LDS base
  unsigned short* Bsl = &Bs[wid * 1024];

  f32x4 acc[4][4] = {};

  const int nk = K >> 5;
  for (int kt = 0; kt < nk; ++kt){
    __syncthreads();                      // protect LDS from overwrite
    gload_lds16(Ag,          Asl);
    gload_lds16(Ag + 16 * K, Asl + 512);
    gload_lds16(Bg,          Bsl);
    gload_lds16(Bg + 16 * K, Bsl + 512);
    Ag += 32; Bg += 32;
    __syncthreads();                      // compiler drains vmcnt(0) here -> data ready

    short8 af[4], bfr[4];
#pragma unroll
    for (int m = 0; m < 4; ++m)
      af[m] = *(const short8*)(&As[(wr * 64 + m * 16 + c15) * 32 + g * 8]);
#pragma unroll
    for (int n = 0; n < 4; ++n)
      bfr[n] = *(const short8*)(&Bs[(wc * 64 + n * 16 + c15) * 32 + g * 8]);
#pragma unroll
    for (int m = 0; m < 4; ++m)
#pragma unroll
      for (int n = 0; n < 4; ++n)
        acc[m][n] = __builtin_amdgcn_mfma_f32_16x16x32_bf16(af[m], bfr[n], acc[m][n], 0, 0, 0);
  }

#pragma unroll
  for (int m = 0; m < 4; ++m)
#pragma unroll
    for (int n = 0; n < 4; ++n){
      int row = m0 + wr * 64 + m * 16 + g * 4;
      int col = n0 + wc * 64 + n * 16 + c15;
      f32x4 v = acc[m][n];
      if (F32OUT){
        float* C = (float*)Cp;
#pragma unroll
        for (int r = 0; r < 4; ++r) C[(size_t)(row + r) * N + col] = v[r];
      } else {
        unsigned short* C = (unsigned short*)Cp;
#pragma unroll
        for (int r = 0; r < 4; ++r) C[(size_t)(row + r) * N + col] = f2bf(v[r]);
      }
    }
}

// ---------------- V transpose: v[s][h*128+d] (stride vstride) -> vt[h][d][s] ----------------
__global__ void transpose_v_kernel(const unsigned short* __restrict__ v, int vstride,
                                   unsigned short* __restrict__ vt){
  __shared__ unsigned short t[64][65];
  int h  = blockIdx.z;
  int d0 = blockIdx.y * 64;
  int s0 = blockIdx.x * 64;
  int c  = threadIdx.x & 63;
  int r0 = threadIdx.x >> 6;
#pragma unroll
  for (int r = r0; r < 64; r += 4) t[r][c] = v[(size_t)(s0 + r) * vstride + h * HD + d0 + c];
  __syncthreads();
#pragma unroll
  for (int r = r0; r < 64; r += 4) vt[(size_t)(h * HD + d0 + r) * SL + s0 + c] = t[c][r];
}

// ---------------- flash attention: causal, GQA 4:1 ----------------
// block = 64 q-rows of one head; 4 waves x 16 rows; KV tile = 64.
// All LDS tiles XOR-swizzled: byte ^= ((row&7)<<4)  (m214 pattern for [R][128/64] bf16).
__global__ __launch_bounds__(256) void flash_attn_kernel(
  const unsigned short* __restrict__ Q,    // row stride QKVN
  const unsigned short* __restrict__ Kb,   // row stride QKVN
  const unsigned short* __restrict__ Vt,   // [kvh*128+d][SL]
  unsigned short* __restrict__ O)          // row stride HID
{
  __shared__ __align__(16) unsigned short Ks[64 * 128];   // stride 256 B
  __shared__ __align__(16) unsigned short Vs[128 * 64];   // stride 128 B
  __shared__ __align__(16) unsigned short Ps[64 * 64];    // stride 128 B
  const int tid = threadIdx.x, lane = tid & 63, wid = tid >> 6;
  const int g = lane >> 4, c15 = lane & 15;
  const int h = blockIdx.x;
  const int qb = gridDim.y - 1 - blockIdx.y;   // heavy causal blocks launch first
  const int kvh = h >> 2;
  const int q0 = qb * 64;

  // Q fragments in registers: A[row=c15][k = kk*32 + g*8 + j]
  short8 aq[4];
  {
    size_t qrow = (size_t)(q0 + wid * 16 + c15) * QKVN + h * HD;
#pragma unroll
    for (int kk = 0; kk < 4; ++kk)
      aq[kk] = *(const short8*)(&Q[qrow + kk * 32 + g * 8]);
  }

  float m_i[4] = {-1e30f, -1e30f, -1e30f, -1e30f};
  float l_i[4] = {0.f, 0.f, 0.f, 0.f};
  f32x4 oacc[8];
#pragma unroll
  for (int df = 0; df < 8; ++df) oacc[df] = (f32x4){0.f, 0.f, 0.f, 0.f};

  const float scale = 0.08838834764831845f;  // 1/sqrt(128)
  const int nt = qb + 1;
  for (int kt = 0; kt < nt; ++kt){
    // stage K tile (64x128) and V^T tile (128x64), swizzled
#pragma unroll
    for (int i = 0; i < 4; ++i){
      int ch = i * 256 + tid;
      { int r = ch >> 4, cob = (ch & 15) * 16;
        *(uint4*)((char*)Ks + r * 256 + (cob ^ ((r & 7) << 4))) =
          *(const uint4*)(&Kb[(size_t)(kt * 64 + r) * QKVN + kvh * HD + (cob >> 1)]); }
      { int r = ch >> 3, cob = (ch & 7) * 16;
        *(uint4*)((char*)Vs + r * 128 + (cob ^ ((r & 7) << 4))) =
          *(const uint4*)(&Vt[(size_t)(kvh * HD + r) * SL + kt * 64 + (cob >> 1)]); }
    }
    __syncthreads();

    // S = Q K^T
    f32x4 sc[4];
#pragma unroll
    for (int f = 0; f < 4; ++f){
      sc[f] = (f32x4){0.f, 0.f, 0.f, 0.f};
#pragma unroll
      for (int kk = 0; kk < 4; ++kk){
        short8 bk = *(const short8*)((const char*)Ks + (f * 16 + c15) * 256 +
                                     ((kk * 64 + g * 16) ^ ((c15 & 7) << 4)));
        sc[f] = __builtin_amdgcn_mfma_f32_16x16x32_bf16(aq[kk], bk, sc[f], 0, 0, 0);
      }
    }

    // mask + online softmax (rows = g*4+r, cols = f*16+c15)
    float p[4][4];
#pragma unroll
    for (int f = 0; f < 4; ++f){
      int col = kt * 64 + f * 16 + c15;
#pragma unroll
      for (int r = 0; r < 4; ++r){
        int row = q0 + wid * 16 + g * 4 + r;
        float s = sc[f][r] * scale;
        p[f][r] = (col <= row) ? s : -1e30f;
      }
    }
#pragma unroll
    for (int r = 0; r < 4; ++r){
      float mx = fmaxf(fmaxf(p[0][r], p[1][r]), fmaxf(p[2][r], p[3][r]));
#pragma unroll
      for (int off = 1; off < 16; off <<= 1) mx = fmaxf(mx, __shfl_xor(mx, off, 64));
      float mnew = fmaxf(m_i[r], mx);
      float cf = __expf(m_i[r] - mnew);
      float rs = 0.f;
#pragma unroll
      for (int f = 0; f < 4; ++f){ float e = __expf(p[f][r] - mnew); p[f][r] = e; rs += e; }
#pragma unroll
      for (int off = 1; off < 16; off <<= 1) rs += __shfl_xor(rs, off, 64);
      l_i[r] = l_i[r] * cf + rs;
      m_i[r] = mnew;
#pragma unroll
      for (int df = 0; df < 8; ++df) oacc[df][r] *= cf;
    }

    // P -> LDS (bf16), swizzled; wave-local rows, no barrier needed before own reads
#pragma unroll
    for (int f = 0; f < 4; ++f)
#pragma unroll
      for (int r = 0; r < 4; ++r){
        int prow = wid * 16 + g * 4 + r;
        *(unsigned short*)((char*)Ps + prow * 128 +
                           ((((f * 16 + c15) * 2)) ^ ((prow & 7) << 4))) = f2bf(p[f][r]);
      }

    // O += P V   (B[k][col=d] = Vt[d][k], contiguous)
#pragma unroll
    for (int kk = 0; kk < 2; ++kk){
      short8 pa = *(const short8*)((const char*)Ps + (wid * 16 + c15) * 128 +
                                   ((kk * 64 + g * 16) ^ ((c15 & 7) << 4)));
#pragma unroll
      for (int df = 0; df < 8; ++df){
        short8 bv = *(const short8*)((const char*)Vs + (df * 16 + c15) * 128 +
                                     ((kk * 64 + g * 16) ^ ((c15 & 7) << 4)));
        oacc[df] = __builtin_amdgcn_mfma_f32_16x16x32_bf16(pa, bv, oacc[df], 0, 0, 0);
      }
    }
    __syncthreads();   // protect Ks/Vs/Ps before next-iter staging
  }

#pragma unroll
  for (int df = 0; df < 8; ++df)
#pragma unroll
    for (int r = 0; r < 4; ++r){
      int row = q0 + wid * 16 + g * 4 + r;
      O[(size_t)row * HID + h * HD + df * 16 + c15] = f2bf(oacc[df][r] / l_i[r]);
    }
}

extern "C" void kernel_launch(void* const* d_in, const int* in_sizes, int n_in,
                              void* d_out, int out_size, void* d_ws, size_t ws_size,
                              hipStream_t stream)
{
  const float* hs  = (const float*)d_in[0];
  const float* qw  = (const float*)d_in[1];
  const float* kw  = (const float*)d_in[2];
  const float* vw  = (const float*)d_in[3];
  const float* ow  = (const float*)d_in[4];
  const int*   pos = (const int*)d_in[5];

  char* w = (char*)d_ws;
  auto alloc = [&](size_t bytes){ char* p = w; w += (bytes + 255) & ~(size_t)255; return p; };
  unsigned short* xb   = (unsigned short*)alloc((size_t)SL * HID * 2);
  unsigned short* wqkv = (unsigned short*)alloc((size_t)QKVN * HID * 2);
  unsigned short* owb  = (unsigned short*)alloc((size_t)HID * HID * 2);
  unsigned short* qkv  = (unsigned short*)alloc((size_t)SL * QKVN * 2);
  unsigned short* vt   = (unsigned short*)alloc((size_t)SL * KVW * 2);
  unsigned short* ab   = (unsigned short*)alloc((size_t)SL * HID * 2);
  float2*         tab  = (float2*)alloc((size_t)SL * 64 * sizeof(float2));

  auto cast = [&](const float* s, unsigned short* d, long n){
    int n8 = (int)(n / 8);
    int blocks = (n8 + 255) / 256; if (blocks > 2048) blocks = 2048;
    cast_f32_bf16<<<blocks, 256, 0, stream>>>(s, (uint4*)d, n8);
  };
  cast(hs, xb, (long)SL * HID);
  cast(qw, wqkv,                              (long)HID * HID);
  cast(kw, wqkv + (size_t)HID * HID,          (long)KVW * HID);
  cast(vw, wqkv + (size_t)(HID + KVW) * HID,  (long)KVW * HID);
  cast(ow, owb,                               (long)HID * HID);

  rope_table_kernel<<<(SL * 64 + 255) / 256, 256, 0, stream>>>(pos, tab);

  // fused QKV projection: [2048][6144] = xb [2048][4096] @ wqkv[6144][4096]^T
  gemm_bt<false><<<dim3(QKVN / 128, SL / 128), 256, 0, stream>>>(xb, wqkv, qkv, SL, QKVN, HID);

  rope_apply_kernel<<<(SL * NH  * 64 + 255) / 256, 256, 0, stream>>>(qkv,        tab, NH,  QKVN);
  rope_apply_kernel<<<(SL * NKV * 64 + 255) / 256, 256, 0, stream>>>(qkv + HID,  tab, NKV, QKVN);

  transpose_v_kernel<<<dim3(SL / 64, HD / 64, NKV), 256, 0, stream>>>(qkv + HID + KVW, QKVN, vt);

  flash_attn_kernel<<<dim3(NH, SL / 64), 256, 0, stream>>>(qkv, qkv + HID, vt, ab);

  gemm_bt<true><<<dim3(HID / 128, SL / 128), 256, 0, stream>>>(ab, owb, d_out, SL, HID, HID);
}

// Round 3
// 427.970 us; speedup vs baseline: 1.5497x; 1.0392x over previous
//
#include <hip/hip_runtime.h>
#include <hip/hip_bf16.h>

#define NH   32
#define NKV  8
#define HD   128
#define SL   2048
#define HID  4096
#define KVW  1024   // NKV*HD
#define QKVN 6144   // HID + 2*KVW

typedef __attribute__((ext_vector_type(8))) short short8;
typedef __attribute__((ext_vector_type(4))) float f32x4;

static __device__ __forceinline__ unsigned short f2bf(float f){
  union { float f; unsigned int i; } v; v.f = f;
  unsigned int r = v.i + 0x7FFFu + ((v.i >> 16) & 1u);
  return (unsigned short)(r >> 16);
}
static __device__ __forceinline__ float bf2f(unsigned short u){
  union { unsigned int i; float f; } v; v.i = ((unsigned int)u) << 16; return v.f;
}
static __device__ __forceinline__ unsigned int pack2(float lo, float hi){
  return (unsigned int)f2bf(lo) | ((unsigned int)f2bf(hi) << 16);
}

// async global -> LDS, 16 B per lane. LDS dest is wave-uniform base + lane*16.
static __device__ __forceinline__ void gload_lds16(const void* g, void* l){
  __builtin_amdgcn_global_load_lds(
      (const __attribute__((address_space(1))) void*)g,
      (__attribute__((address_space(3))) void*)l,
      16, 0, 0);
}

// ---------------- cast fp32 -> bf16, 8 elems/thread ----------------
__global__ void cast_f32_bf16(const float* __restrict__ src, uint4* __restrict__ dst, int n8){
  int stride = gridDim.x * blockDim.x;
  for (int i = blockIdx.x * blockDim.x + threadIdx.x; i < n8; i += stride){
    float4 a = ((const float4*)src)[2*i + 0];
    float4 b = ((const float4*)src)[2*i + 1];
    uint4 o;
    o.x = pack2(a.x, a.y); o.y = pack2(a.z, a.w);
    o.z = pack2(b.x, b.y); o.w = pack2(b.z, b.w);
    dst[i] = o;
  }
}

// ---------------- RoPE cos/sin table ----------------
__global__ void rope_table_kernel(const int* __restrict__ pos, float2* __restrict__ tab){
  int i = blockIdx.x * blockDim.x + threadIdx.x;
  if (i >= SL * 64) return;
  int s = i >> 6, f = i & 63;
  float inv = expf(-((float)(2 * f) / 128.0f) * 9.210340371976184f);
  float ang = (float)pos[s] * inv;
  float sn, cs;
  sincosf(ang, &sn, &cs);
  tab[i] = make_float2(cs, sn);
}

// ---------------- in-place RoPE on bf16 [s][stride] ----------------
__global__ void rope_apply_kernel(unsigned short* x, const float2* __restrict__ tab,
                                  int nheads, int rowstride){
  int i = blockIdx.x * blockDim.x + threadIdx.x;
  int total = SL * nheads * 64;
  if (i >= total) return;
  int f = i & 63;
  int t = i >> 6;
  int h = t % nheads;
  int s = t / nheads;
  float2 cs = tab[s * 64 + f];
  size_t base = (size_t)s * rowstride + h * HD;
  float x1 = bf2f(x[base + f]);
  float x2 = bf2f(x[base + f + 64]);
  x[base + f]      = f2bf(x1 * cs.x - x2 * cs.y);
  x[base + f + 64] = f2bf(x2 * cs.x + x1 * cs.y);
}

// ================= 8-phase bt-GEMM: C[M][N] = A[M][K] * B[N][K]^T =================
// BM=128, BN=256, BK=64 stored as two kk-split [rows][32] LDS sub-tiles (conflict-
// free ds_read_b128, gload_lds-compatible, no swizzle needed). 8 waves (2Mx4N),
// per-wave 64x64. Double-buffered; counted vmcnt (never 0 mid-loop); setprio on
// MFMA clusters. Per-wave issue order per K-tile: [Ak0, Ak1, B00, B01, B10, B11]
// so vmcnt(2) @p0 guarantees A(both)+B-kk0, vmcnt(4) @p2 guarantees B-kk1.
template<bool F32OUT>
__global__ __launch_bounds__(512, 2) void gemm_bt8(
  const unsigned short* __restrict__ A,
  const unsigned short* __restrict__ B,
  void* __restrict__ Cp, int M, int N, int K)
{
  __shared__ __align__(16) unsigned short As[2 * 2 * 128 * 32];  // [buf][kk][row][32]
  __shared__ __align__(16) unsigned short Bs[2 * 2 * 256 * 32];  // [buf][kk][row][32]
  const int tid = threadIdx.x;
  const int lane = tid & 63, wid = tid >> 6;     // 8 waves
  const int g = lane >> 4, c15 = lane & 15;
  const int wr = wid >> 2, wn = wid & 3;         // 2 x 4 wave grid

  // bijective XCD swizzle (grid % 8 == 0 for all our launches)
  int nwg = gridDim.x * gridDim.y;
  int lin = blockIdx.y * gridDim.x + blockIdx.x;
  int cpx = nwg >> 3;
  int swz = (lin & 7) * cpx + (lin >> 3);
  const int n0 = (swz % gridDim.x) * 256;
  const int m0 = (swz / gridDim.x) * 128;

  // staging lane mapping: each wave-load = 16 rows x 32 k-elems (1 KiB linear)
  const int srow = lane >> 2;           // 0..15
  const int scol = (lane & 3) * 8;      // 0,8,16,24 elems
  const unsigned short* Agl = &A[(size_t)(m0 + wid * 16 + srow) * K + scol];
  const unsigned short* Bgl = &B[(size_t)(n0 + wid * 32 + srow) * K + scol];
  const size_t BK16 = (size_t)16 * K;

  f32x4 acc[4][4] = {};

  // prologue: stage tile 0 into buf 0
  gload_lds16(Agl,             &As[(0 * 128 + wid * 16) * 32]);
  gload_lds16(Agl + 32,        &As[(1 * 128 + wid * 16) * 32]);
  gload_lds16(Bgl,             &Bs[(0 * 256 + wid * 32) * 32]);
  gload_lds16(Bgl + BK16,      &Bs[(0 * 256 + wid * 32 + 16) * 32]);
  gload_lds16(Bgl + 32,        &Bs[(1 * 256 + wid * 32) * 32]);
  gload_lds16(Bgl + BK16 + 32, &Bs[(1 * 256 + wid * 32 + 16) * 32]);

  const int nk2 = K >> 6;
  int cur = 0;
  for (int t = 0; t < nk2; ++t){
    const int k1 = (t + 1) << 6;
    const bool pf = (t + 1 < nk2);
    const int nb = cur ^ 1;
    short8 af[4], bf[4];

    // ---------- phase 0: kk0, n{0,1}; prefetch next A ----------
    asm volatile("s_waitcnt vmcnt(2)" ::: "memory");
    __builtin_amdgcn_s_barrier();
#pragma unroll
    for (int m = 0; m < 4; ++m)
      af[m] = *(const short8*)(&As[((cur*2+0)*128 + wr*64 + m*16 + c15)*32 + g*8]);
    bf[0] = *(const short8*)(&Bs[((cur*2+0)*256 + wn*64 +  0 + c15)*32 + g*8]);
    bf[1] = *(const short8*)(&Bs[((cur*2+0)*256 + wn*64 + 16 + c15)*32 + g*8]);
    if (pf){
      gload_lds16(Agl + k1,      &As[((nb*2+0)*128 + wid*16)*32]);
      gload_lds16(Agl + k1 + 32, &As[((nb*2+1)*128 + wid*16)*32]);
      asm volatile("" ::: "memory");
    }
    __builtin_amdgcn_s_setprio(1);
#pragma unroll
    for (int m = 0; m < 4; ++m){
      acc[m][0] = __builtin_amdgcn_mfma_f32_16x16x32_bf16(af[m], bf[0], acc[m][0], 0, 0, 0);
      acc[m][1] = __builtin_amdgcn_mfma_f32_16x16x32_bf16(af[m], bf[1], acc[m][1], 0, 0, 0);
    }
    __builtin_amdgcn_s_setprio(0);

    // ---------- phase 1: kk0, n{2,3}; prefetch next B-kk0 ----------
    __builtin_amdgcn_s_barrier();
    bf[2] = *(const short8*)(&Bs[((cur*2+0)*256 + wn*64 + 32 + c15)*32 + g*8]);
    bf[3] = *(const short8*)(&Bs[((cur*2+0)*256 + wn*64 + 48 + c15)*32 + g*8]);
    if (pf){
      gload_lds16(Bgl + k1,        &Bs[((nb*2+0)*256 + wid*32)*32]);
      gload_lds16(Bgl + BK16 + k1, &Bs[((nb*2+0)*256 + wid*32 + 16)*32]);
      asm volatile("" ::: "memory");
    }
    __builtin_amdgcn_s_setprio(1);
#pragma unroll
    for (int m = 0; m < 4; ++m){
      acc[m][2] = __builtin_amdgcn_mfma_f32_16x16x32_bf16(af[m], bf[2], acc[m][2], 0, 0, 0);
      acc[m][3] = __builtin_amdgcn_mfma_f32_16x16x32_bf16(af[m], bf[3], acc[m][3], 0, 0, 0);
    }
    __builtin_amdgcn_s_setprio(0);

    // ---------- phase 2: kk1, n{0,1}; prefetch next B-kk1 ----------
    if (pf) asm volatile("s_waitcnt vmcnt(4)" ::: "memory");
    else    asm volatile("s_waitcnt vmcnt(0)" ::: "memory");
    __builtin_amdgcn_s_barrier();
#pragma unroll
    for (int m = 0; m < 4; ++m)
      af[m] = *(const short8*)(&As[((cur*2+1)*128 + wr*64 + m*16 + c15)*32 + g*8]);
    bf[0] = *(const short8*)(&Bs[((cur*2+1)*256 + wn*64 +  0 + c15)*32 + g*8]);
    bf[1] = *(const short8*)(&Bs[((cur*2+1)*256 + wn*64 + 16 + c15)*32 + g*8]);
    if (pf){
      gload_lds16(Bgl + k1 + 32,        &Bs[((nb*2+1)*256 + wid*32)*32]);
      gload_lds16(Bgl + BK16 + k1 + 32, &Bs[((nb*2+1)*256 + wid*32 + 16)*32]);
      asm volatile("" ::: "memory");
    }
    __builtin_amdgcn_s_setprio(1);
#pragma unroll
    for (int m = 0; m < 4; ++m){
      acc[m][0] = __builtin_amdgcn_mfma_f32_16x16x32_bf16(af[m], bf[0], acc[m][0], 0, 0, 0);
      acc[m][1] = __builtin_amdgcn_mfma_f32_16x16x32_bf16(af[m], bf[1], acc[m][1], 0, 0, 0);
    }
    __builtin_amdgcn_s_setprio(0);

    // ---------- phase 3: kk1, n{2,3} ----------
    __builtin_amdgcn_s_barrier();
    bf[2] = *(const short8*)(&Bs[((cur*2+1)*256 + wn*64 + 32 + c15)*32 + g*8]);
    bf[3] = *(const short8*)(&Bs[((cur*2+1)*256 + wn*64 + 48 + c15)*32 + g*8]);
    __builtin_amdgcn_s_setprio(1);
#pragma unroll
    for (int m = 0; m < 4; ++m){
      acc[m][2] = __builtin_amdgcn_mfma_f32_16x16x32_bf16(af[m], bf[2], acc[m][2], 0, 0, 0);
      acc[m][3] = __builtin_amdgcn_mfma_f32_16x16x32_bf16(af[m], bf[3], acc[m][3], 0, 0, 0);
    }
    __builtin_amdgcn_s_setprio(0);
    cur = nb;
  }

#pragma unroll
  for (int m = 0; m < 4; ++m)
#pragma unroll
    for (int n = 0; n < 4; ++n){
      int row = m0 + wr * 64 + m * 16 + g * 4;
      int col = n0 + wn * 64 + n * 16 + c15;
      f32x4 v = acc[m][n];
      if (F32OUT){
        float* C = (float*)Cp;
#pragma unroll
        for (int r = 0; r < 4; ++r) C[(size_t)(row + r) * N + col] = v[r];
      } else {
        unsigned short* C = (unsigned short*)Cp;
#pragma unroll
        for (int r = 0; r < 4; ++r) C[(size_t)(row + r) * N + col] = f2bf(v[r]);
      }
    }
}

// ---------------- V transpose: v[s][h*128+d] (stride vstride) -> vt[h][d][s] ----------------
__global__ void transpose_v_kernel(const unsigned short* __restrict__ v, int vstride,
                                   unsigned short* __restrict__ vt){
  __shared__ unsigned short t[64][65];
  int h  = blockIdx.z;
  int d0 = blockIdx.y * 64;
  int s0 = blockIdx.x * 64;
  int c  = threadIdx.x & 63;
  int r0 = threadIdx.x >> 6;
#pragma unroll
  for (int r = r0; r < 64; r += 4) t[r][c] = v[(size_t)(s0 + r) * vstride + h * HD + d0 + c];
  __syncthreads();
#pragma unroll
  for (int r = r0; r < 64; r += 4) vt[(size_t)(h * HD + d0 + r) * SL + s0 + c] = t[c][r];
}

// ---------------- flash attention: causal, GQA 4:1 ----------------
__global__ __launch_bounds__(256) void flash_attn_kernel(
  const unsigned short* __restrict__ Q,    // row stride QKVN
  const unsigned short* __restrict__ Kb,   // row stride QKVN
  const unsigned short* __restrict__ Vt,   // [kvh*128+d][SL]
  unsigned short* __restrict__ O)          // row stride HID
{
  __shared__ __align__(16) unsigned short Ks[64 * 128];   // stride 256 B
  __shared__ __align__(16) unsigned short Vs[128 * 64];   // stride 128 B
  __shared__ __align__(16) unsigned short Ps[64 * 64];    // stride 128 B
  const int tid = threadIdx.x, lane = tid & 63, wid = tid >> 6;
  const int g = lane >> 4, c15 = lane & 15;
  const int h = blockIdx.x;
  const int qb = gridDim.y - 1 - blockIdx.y;   // heavy causal blocks launch first
  const int kvh = h >> 2;
  const int q0 = qb * 64;

  short8 aq[4];
  {
    size_t qrow = (size_t)(q0 + wid * 16 + c15) * QKVN + h * HD;
#pragma unroll
    for (int kk = 0; kk < 4; ++kk)
      aq[kk] = *(const short8*)(&Q[qrow + kk * 32 + g * 8]);
  }

  float m_i[4] = {-1e30f, -1e30f, -1e30f, -1e30f};
  float l_i[4] = {0.f, 0.f, 0.f, 0.f};
  f32x4 oacc[8];
#pragma unroll
  for (int df = 0; df < 8; ++df) oacc[df] = (f32x4){0.f, 0.f, 0.f, 0.f};

  const float scale = 0.08838834764831845f;  // 1/sqrt(128)
  const int nt = qb + 1;
  for (int kt = 0; kt < nt; ++kt){
#pragma unroll
    for (int i = 0; i < 4; ++i){
      int ch = i * 256 + tid;
      { int r = ch >> 4, cob = (ch & 15) * 16;
        *(uint4*)((char*)Ks + r * 256 + (cob ^ ((r & 7) << 4))) =
          *(const uint4*)(&Kb[(size_t)(kt * 64 + r) * QKVN + kvh * HD + (cob >> 1)]); }
      { int r = ch >> 3, cob = (ch & 7) * 16;
        *(uint4*)((char*)Vs + r * 128 + (cob ^ ((r & 7) << 4))) =
          *(const uint4*)(&Vt[(size_t)(kvh * HD + r) * SL + kt * 64 + (cob >> 1)]); }
    }
    __syncthreads();

    // S = Q K^T
    f32x4 sc[4];
    __builtin_amdgcn_s_setprio(1);
#pragma unroll
    for (int f = 0; f < 4; ++f){
      sc[f] = (f32x4){0.f, 0.f, 0.f, 0.f};
#pragma unroll
      for (int kk = 0; kk < 4; ++kk){
        short8 bk = *(const short8*)((const char*)Ks + (f * 16 + c15) * 256 +
                                     ((kk * 64 + g * 16) ^ ((c15 & 7) << 4)));
        sc[f] = __builtin_amdgcn_mfma_f32_16x16x32_bf16(aq[kk], bk, sc[f], 0, 0, 0);
      }
    }
    __builtin_amdgcn_s_setprio(0);

    // mask + online softmax (rows = g*4+r, cols = f*16+c15)
    float p[4][4];
#pragma unroll
    for (int f = 0; f < 4; ++f){
      int col = kt * 64 + f * 16 + c15;
#pragma unroll
      for (int r = 0; r < 4; ++r){
        int row = q0 + wid * 16 + g * 4 + r;
        float s = sc[f][r] * scale;
        p[f][r] = (col <= row) ? s : -1e30f;
      }
    }
#pragma unroll
    for (int r = 0; r < 4; ++r){
      float mx = fmaxf(fmaxf(p[0][r], p[1][r]), fmaxf(p[2][r], p[3][r]));
#pragma unroll
      for (int off = 1; off < 16; off <<= 1) mx = fmaxf(mx, __shfl_xor(mx, off, 64));
      float mnew = fmaxf(m_i[r], mx);
      float cf = __expf(m_i[r] - mnew);
      float rs = 0.f;
#pragma unroll
      for (int f = 0; f < 4; ++f){ float e = __expf(p[f][r] - mnew); p[f][r] = e; rs += e; }
#pragma unroll
      for (int off = 1; off < 16; off <<= 1) rs += __shfl_xor(rs, off, 64);
      l_i[r] = l_i[r] * cf + rs;
      m_i[r] = mnew;
#pragma unroll
      for (int df = 0; df < 8; ++df) oacc[df][r] *= cf;
    }

    // P -> LDS (bf16), swizzled; wave-local rows
#pragma unroll
    for (int f = 0; f < 4; ++f)
#pragma unroll
      for (int r = 0; r < 4; ++r){
        int prow = wid * 16 + g * 4 + r;
        *(unsigned short*)((char*)Ps + prow * 128 +
                           ((((f * 16 + c15) * 2)) ^ ((prow & 7) << 4))) = f2bf(p[f][r]);
      }

    // O += P V
    __builtin_amdgcn_s_setprio(1);
#pragma unroll
    for (int kk = 0; kk < 2; ++kk){
      short8 pa = *(const short8*)((const char*)Ps + (wid * 16 + c15) * 128 +
                                   ((kk * 64 + g * 16) ^ ((c15 & 7) << 4)));
#pragma unroll
      for (int df = 0; df < 8; ++df){
        short8 bv = *(const short8*)((const char*)Vs + (df * 16 + c15) * 128 +
                                     ((kk * 64 + g * 16) ^ ((c15 & 7) << 4)));
        oacc[df] = __builtin_amdgcn_mfma_f32_16x16x32_bf16(pa, bv, oacc[df], 0, 0, 0);
      }
    }
    __builtin_amdgcn_s_setprio(0);
    __syncthreads();
  }

#pragma unroll
  for (int df = 0; df < 8; ++df)
#pragma unroll
    for (int r = 0; r < 4; ++r){
      int row = q0 + wid * 16 + g * 4 + r;
      O[(size_t)row * HID + h * HD + df * 16 + c15] = f2bf(oacc[df][r] / l_i[r]);
    }
}

extern "C" void kernel_launch(void* const* d_in, const int* in_sizes, int n_in,
                              void* d_out, int out_size, void* d_ws, size_t ws_size,
                              hipStream_t stream)
{
  const float* hs  = (const float*)d_in[0];
  const float* qw  = (const float*)d_in[1];
  const float* kw  = (const float*)d_in[2];
  const float* vw  = (const float*)d_in[3];
  const float* ow  = (const float*)d_in[4];
  const int*   pos = (const int*)d_in[5];

  char* w = (char*)d_ws;
  auto alloc = [&](size_t bytes){ char* p = w; w += (bytes + 255) & ~(size_t)255; return p; };
  unsigned short* xb   = (unsigned short*)alloc((size_t)SL * HID * 2);
  unsigned short* wqkv = (unsigned short*)alloc((size_t)QKVN * HID * 2);
  unsigned short* owb  = (unsigned short*)alloc((size_t)HID * HID * 2);
  unsigned short* qkv  = (unsigned short*)alloc((size_t)SL * QKVN * 2);
  unsigned short* vt   = (unsigned short*)alloc((size_t)SL * KVW * 2);
  unsigned short* ab   = (unsigned short*)alloc((size_t)SL * HID * 2);
  float2*         tab  = (float2*)alloc((size_t)SL * 64 * sizeof(float2));

  auto cast = [&](const float* s, unsigned short* d, long n){
    int n8 = (int)(n / 8);
    int blocks = (n8 + 255) / 256; if (blocks > 2048) blocks = 2048;
    cast_f32_bf16<<<blocks, 256, 0, stream>>>(s, (uint4*)d, n8);
  };
  cast(hs, xb, (long)SL * HID);
  cast(qw, wqkv,                              (long)HID * HID);
  cast(kw, wqkv + (size_t)HID * HID,          (long)KVW * HID);
  cast(vw, wqkv + (size_t)(HID + KVW) * HID,  (long)KVW * HID);
  cast(ow, owb,                               (long)HID * HID);

  rope_table_kernel<<<(SL * 64 + 255) / 256, 256, 0, stream>>>(pos, tab);

  // fused QKV projection: [2048][6144] = xb [2048][4096] @ wqkv[6144][4096]^T
  gemm_bt8<false><<<dim3(QKVN / 256, SL / 128), 512, 0, stream>>>(xb, wqkv, qkv, SL, QKVN, HID);

  rope_apply_kernel<<<(SL * NH  * 64 + 255) / 256, 256, 0, stream>>>(qkv,        tab, NH,  QKVN);
  rope_apply_kernel<<<(SL * NKV * 64 + 255) / 256, 256, 0, stream>>>(qkv + HID,  tab, NKV, QKVN);

  transpose_v_kernel<<<dim3(SL / 64, HD / 64, NKV), 256, 0, stream>>>(qkv + HID + KVW, QKVN, vt);

  flash_attn_kernel<<<dim3(NH, SL / 64), 256, 0, stream>>>(qkv, qkv + HID, vt, ab);

  gemm_bt8<true><<<dim3(HID / 256, SL / 128), 512, 0, stream>>>(ab, owb, d_out, SL, HID, HID);
}

// Round 4
// 415.827 us; speedup vs baseline: 1.5950x; 1.0292x over previous
//
#include <hip/hip_runtime.h>
#include <hip/hip_bf16.h>

#define NH   32
#define NKV  8
#define HD   128
#define SL   2048
#define HID  4096
#define KVW  1024   // NKV*HD
#define QKVN 6144   // HID + 2*KVW

typedef __attribute__((ext_vector_type(8))) short short8;
typedef __attribute__((ext_vector_type(4))) float f32x4;

static __device__ __forceinline__ unsigned short f2bf(float f){
  union { float f; unsigned int i; } v; v.f = f;
  unsigned int r = v.i + 0x7FFFu + ((v.i >> 16) & 1u);
  return (unsigned short)(r >> 16);
}
static __device__ __forceinline__ float bf2f(unsigned short u){
  union { unsigned int i; float f; } v; v.i = ((unsigned int)u) << 16; return v.f;
}
static __device__ __forceinline__ unsigned int pack2(float lo, float hi){
  return (unsigned int)f2bf(lo) | ((unsigned int)f2bf(hi) << 16);
}

// async global -> LDS, 16 B per lane. LDS dest is wave-uniform base + lane*16.
static __device__ __forceinline__ void gload_lds16(const void* g, void* l){
  __builtin_amdgcn_global_load_lds(
      (const __attribute__((address_space(1))) void*)g,
      (__attribute__((address_space(3))) void*)l,
      16, 0, 0);
}

// ---------------- cast fp32 -> bf16, 8 elems/thread ----------------
__global__ void cast_f32_bf16(const float* __restrict__ src, uint4* __restrict__ dst, int n8){
  int stride = gridDim.x * blockDim.x;
  for (int i = blockIdx.x * blockDim.x + threadIdx.x; i < n8; i += stride){
    float4 a = ((const float4*)src)[2*i + 0];
    float4 b = ((const float4*)src)[2*i + 1];
    uint4 o;
    o.x = pack2(a.x, a.y); o.y = pack2(a.z, a.w);
    o.z = pack2(b.x, b.y); o.w = pack2(b.z, b.w);
    dst[i] = o;
  }
}

// ---------------- RoPE cos/sin table ----------------
__global__ void rope_table_kernel(const int* __restrict__ pos, float2* __restrict__ tab){
  int i = blockIdx.x * blockDim.x + threadIdx.x;
  if (i >= SL * 64) return;
  int s = i >> 6, f = i & 63;
  float inv = expf(-((float)(2 * f) / 128.0f) * 9.210340371976184f);
  float ang = (float)pos[s] * inv;
  float sn, cs;
  sincosf(ang, &sn, &cs);
  tab[i] = make_float2(cs, sn);
}

// ---------------- in-place RoPE on bf16 [s][stride] ----------------
__global__ void rope_apply_kernel(unsigned short* x, const float2* __restrict__ tab,
                                  int nheads, int rowstride){
  int i = blockIdx.x * blockDim.x + threadIdx.x;
  int total = SL * nheads * 64;
  if (i >= total) return;
  int f = i & 63;
  int t = i >> 6;
  int h = t % nheads;
  int s = t / nheads;
  float2 cs = tab[s * 64 + f];
  size_t base = (size_t)s * rowstride + h * HD;
  float x1 = bf2f(x[base + f]);
  float x2 = bf2f(x[base + f + 64]);
  x[base + f]      = f2bf(x1 * cs.x - x2 * cs.y);
  x[base + f + 64] = f2bf(x2 * cs.x + x1 * cs.y);
}

// ========== bt-GEMM: C[M][N] = A[M][K] * B[N][K]^T ==========
// 128x128 tile, BK=32, 4 waves (2x2), gload_lds staging, DOUBLE-buffered,
// ONE barrier per K-step. 2D-rectangle XCD swizzle: one 8m x RN rect per XCD
// (m-major inside) so co-resident blocks share A and B panels in L2.
template<bool F32OUT>
__global__ __launch_bounds__(256) void gemm_bt(
  const unsigned short* __restrict__ A,
  const unsigned short* __restrict__ B,
  void* __restrict__ Cp, int M, int N, int K)
{
  __shared__ __align__(16) unsigned short As[2][128 * 32];
  __shared__ __align__(16) unsigned short Bs[2][128 * 32];
  const int tid = threadIdx.x;
  const int lane = tid & 63, wid = tid >> 6;
  const int g = lane >> 4, c15 = lane & 15;
  const int wr = wid >> 1, wc = wid & 1;

  // ---- 2D rect XCD swizzle ----
  const int gx = gridDim.x, gy = gridDim.y;
  const int nwg = gx * gy;
  const int lin = blockIdx.y * gx + blockIdx.x;
  int mb, nb;
  const int cpx = nwg >> 3;            // blocks per XCD
  const int RN  = cpx >> 3;            // rect = 8(m) x RN(n)
  if (RN > 0 && (gy & 7) == 0 && (cpx & 7) == 0 && gx % RN == 0 && (8 % (gx / RN)) == 0){
    int xcd = lin & 7, j = lin >> 3;
    int nrc = gx / RN;                 // rect columns across chip
    int rr = xcd / nrc, rc = xcd % nrc;
    mb = rr * 8 + (j & 7);             // m-major within rect
    nb = rc * RN + (j >> 3);
  } else {
    mb = lin / gx; nb = lin % gx;
  }
  const int m0 = mb * 128, n0 = nb * 128;

  // staging: wave wid covers rows [wid*32, wid*32+32), 2 issues of 16 rows each side
  const int srow = wid * 32 + (lane >> 2);
  const int scol = (lane & 3) * 8;
  const unsigned short* Ag = &A[(size_t)(m0 + srow) * K + scol];
  const unsigned short* Bg = &B[(size_t)(n0 + srow) * K + scol];
  const size_t K16 = (size_t)16 * K;

  f32x4 acc[4][4] = {};

  // prologue: stage tile 0 into buf 0
  gload_lds16(Ag,       &As[0][wid * 1024]);
  gload_lds16(Ag + K16, &As[0][wid * 1024 + 512]);
  gload_lds16(Bg,       &Bs[0][wid * 1024]);
  gload_lds16(Bg + K16, &Bs[0][wid * 1024 + 512]);
  __syncthreads();   // drains vmcnt(0) + barrier

  const int nk = K >> 5;
  for (int t = 0; t < nk; ++t){
    const int cur = t & 1;
    if (t + 1 < nk){
      const unsigned short* a2 = Ag + (size_t)(t + 1) * 32;
      const unsigned short* b2 = Bg + (size_t)(t + 1) * 32;
      const int nb2 = cur ^ 1;
      gload_lds16(a2,       &As[nb2][wid * 1024]);
      gload_lds16(a2 + K16, &As[nb2][wid * 1024 + 512]);
      gload_lds16(b2,       &Bs[nb2][wid * 1024]);
      gload_lds16(b2 + K16, &Bs[nb2][wid * 1024 + 512]);
    }
    short8 af[4], bfr[4];
#pragma unroll
    for (int m = 0; m < 4; ++m)
      af[m] = *(const short8*)(&As[cur][(wr * 64 + m * 16 + c15) * 32 + g * 8]);
#pragma unroll
    for (int n = 0; n < 4; ++n)
      bfr[n] = *(const short8*)(&Bs[cur][(wc * 64 + n * 16 + c15) * 32 + g * 8]);
#pragma unroll
    for (int m = 0; m < 4; ++m)
#pragma unroll
      for (int n = 0; n < 4; ++n)
        acc[m][n] = __builtin_amdgcn_mfma_f32_16x16x32_bf16(af[m], bfr[n], acc[m][n], 0, 0, 0);
    __syncthreads();   // drains stage loads + protects both buffers
  }

#pragma unroll
  for (int m = 0; m < 4; ++m)
#pragma unroll
    for (int n = 0; n < 4; ++n){
      int row = m0 + wr * 64 + m * 16 + g * 4;
      int col = n0 + wc * 64 + n * 16 + c15;
      f32x4 v = acc[m][n];
      if (F32OUT){
        float* C = (float*)Cp;
#pragma unroll
        for (int r = 0; r < 4; ++r) C[(size_t)(row + r) * N + col] = v[r];
      } else {
        unsigned short* C = (unsigned short*)Cp;
#pragma unroll
        for (int r = 0; r < 4; ++r) C[(size_t)(row + r) * N + col] = f2bf(v[r]);
      }
    }
}

// ---------------- V transpose: v[s][h*128+d] (stride vstride) -> vt[h][d][s] ----------------
__global__ void transpose_v_kernel(const unsigned short* __restrict__ v, int vstride,
                                   unsigned short* __restrict__ vt){
  __shared__ unsigned short t[64][65];
  int h  = blockIdx.z;
  int d0 = blockIdx.y * 64;
  int s0 = blockIdx.x * 64;
  int c  = threadIdx.x & 63;
  int r0 = threadIdx.x >> 6;
#pragma unroll
  for (int r = r0; r < 64; r += 4) t[r][c] = v[(size_t)(s0 + r) * vstride + h * HD + d0 + c];
  __syncthreads();
#pragma unroll
  for (int r = r0; r < 64; r += 4) vt[(size_t)(h * HD + d0 + r) * SL + s0 + c] = t[c][r];
}

// ---------------- flash attention: causal, GQA-shared K/V staging ----------------
// block = 512 threads (8 waves) = 4 q-heads of one KV group x 32 q-rows.
// wave role: head = kvh*4 + (wid&3), row-group = wid>>2 (16 rows each).
// K/V staged ONCE per kv-tile for all 4 heads. Softmax in exp2 domain.
__global__ __launch_bounds__(512) void flash_attn_kernel(
  const unsigned short* __restrict__ Q,    // row stride QKVN
  const unsigned short* __restrict__ Kb,   // row stride QKVN
  const unsigned short* __restrict__ Vt,   // [kvh*128+d][SL]
  unsigned short* __restrict__ O)          // row stride HID
{
  __shared__ __align__(16) unsigned short Ks[64 * 128];    // stride 256 B, swizzled
  __shared__ __align__(16) unsigned short Vs[128 * 64];    // stride 128 B, swizzled
  __shared__ __align__(16) unsigned short Ps[128 * 64];    // per-wave rows, swizzled
  const int tid = threadIdx.x, lane = tid & 63, wid = tid >> 6;
  const int g = lane >> 4, c15 = lane & 15;
  const int kvh = blockIdx.x;
  const int yy = blockIdx.y;
  const int qb = (yy & 1) ? (yy >> 1) : (63 - (yy >> 1));   // heavy/light interleave
  const int h = kvh * 4 + (wid & 3);
  const int rg = wid >> 2;
  const int q0 = qb * 32;

  short8 aq[4];
  {
    size_t qrow = (size_t)(q0 + rg * 16 + c15) * QKVN + h * HD;
#pragma unroll
    for (int kk = 0; kk < 4; ++kk)
      aq[kk] = *(const short8*)(&Q[qrow + kk * 32 + g * 8]);
  }

  float m_i[4] = {-1e30f, -1e30f, -1e30f, -1e30f};
  float l_i[4] = {0.f, 0.f, 0.f, 0.f};
  f32x4 oacc[8];
#pragma unroll
  for (int df = 0; df < 8; ++df) oacc[df] = (f32x4){0.f, 0.f, 0.f, 0.f};

  const float scl2 = 0.08838834764831845f * 1.4426950408889634f;  // 1/sqrt(128)*log2e
  const int nt = (q0 + 31) / 64 + 1;
  for (int kt = 0; kt < nt; ++kt){
    // stage K (64x128) + V^T (128x64), swizzled, 512 threads x 2 chunks each
#pragma unroll
    for (int i = 0; i < 2; ++i){
      int ch = i * 512 + tid;
      { int r = ch >> 4, cob = (ch & 15) * 16;
        *(uint4*)((char*)Ks + r * 256 + (cob ^ ((r & 7) << 4))) =
          *(const uint4*)(&Kb[(size_t)(kt * 64 + r) * QKVN + kvh * HD + (cob >> 1)]); }
      { int r = ch >> 3, cob = (ch & 7) * 16;
        *(uint4*)((char*)Vs + r * 128 + (cob ^ ((r & 7) << 4))) =
          *(const uint4*)(&Vt[(size_t)(kvh * HD + r) * SL + kt * 64 + (cob >> 1)]); }
    }
    __syncthreads();

    // S = Q K^T
    f32x4 sc[4];
    __builtin_amdgcn_s_setprio(1);
#pragma unroll
    for (int f = 0; f < 4; ++f){
      sc[f] = (f32x4){0.f, 0.f, 0.f, 0.f};
#pragma unroll
      for (int kk = 0; kk < 4; ++kk){
        short8 bk = *(const short8*)((const char*)Ks + (f * 16 + c15) * 256 +
                                     ((kk * 64 + g * 16) ^ ((c15 & 7) << 4)));
        sc[f] = __builtin_amdgcn_mfma_f32_16x16x32_bf16(aq[kk], bk, sc[f], 0, 0, 0);
      }
    }
    __builtin_amdgcn_s_setprio(0);

    // mask + online softmax in exp2 domain (rows = g*4+r, cols = f*16+c15)
    float p[4][4];
#pragma unroll
    for (int f = 0; f < 4; ++f){
      int col = kt * 64 + f * 16 + c15;
#pragma unroll
      for (int r = 0; r < 4; ++r){
        int row = q0 + rg * 16 + g * 4 + r;
        p[f][r] = (col <= row) ? sc[f][r] * scl2 : -1e30f;
      }
    }
#pragma unroll
    for (int r = 0; r < 4; ++r){
      float mx = fmaxf(fmaxf(p[0][r], p[1][r]), fmaxf(p[2][r], p[3][r]));
#pragma unroll
      for (int off = 1; off < 16; off <<= 1) mx = fmaxf(mx, __shfl_xor(mx, off, 64));
      float mnew = fmaxf(m_i[r], mx);
      float cf = exp2f(m_i[r] - mnew);
      float rs = 0.f;
#pragma unroll
      for (int f = 0; f < 4; ++f){ float e = exp2f(p[f][r] - mnew); p[f][r] = e; rs += e; }
#pragma unroll
      for (int off = 1; off < 16; off <<= 1) rs += __shfl_xor(rs, off, 64);
      l_i[r] = l_i[r] * cf + rs;
      m_i[r] = mnew;
#pragma unroll
      for (int df = 0; df < 8; ++df) oacc[df][r] *= cf;
    }

    // P -> LDS (bf16), swizzled; wave-local rows (wid*16 .. +16)
#pragma unroll
    for (int f = 0; f < 4; ++f)
#pragma unroll
      for (int r = 0; r < 4; ++r){
        int prow = wid * 16 + g * 4 + r;
        *(unsigned short*)((char*)Ps + prow * 128 +
                           ((((f * 16 + c15) * 2)) ^ ((prow & 7) << 4))) = f2bf(p[f][r]);
      }

    // O += P V
    __builtin_amdgcn_s_setprio(1);
#pragma unroll
    for (int kk = 0; kk < 2; ++kk){
      short8 pa = *(const short8*)((const char*)Ps + (wid * 16 + c15) * 128 +
                                   ((kk * 64 + g * 16) ^ ((c15 & 7) << 4)));
#pragma unroll
      for (int df = 0; df < 8; ++df){
        short8 bv = *(const short8*)((const char*)Vs + (df * 16 + c15) * 128 +
                                     ((kk * 64 + g * 16) ^ ((c15 & 7) << 4)));
        oacc[df] = __builtin_amdgcn_mfma_f32_16x16x32_bf16(pa, bv, oacc[df], 0, 0, 0);
      }
    }
    __builtin_amdgcn_s_setprio(0);
    __syncthreads();   // protect Ks/Vs before next-iter staging
  }

#pragma unroll
  for (int df = 0; df < 8; ++df)
#pragma unroll
    for (int r = 0; r < 4; ++r){
      int row = q0 + rg * 16 + g * 4 + r;
      O[(size_t)row * HID + h * HD + df * 16 + c15] = f2bf(oacc[df][r] / l_i[r]);
    }
}

extern "C" void kernel_launch(void* const* d_in, const int* in_sizes, int n_in,
                              void* d_out, int out_size, void* d_ws, size_t ws_size,
                              hipStream_t stream)
{
  const float* hs  = (const float*)d_in[0];
  const float* qw  = (const float*)d_in[1];
  const float* kw  = (const float*)d_in[2];
  const float* vw  = (const float*)d_in[3];
  const float* ow  = (const float*)d_in[4];
  const int*   pos = (const int*)d_in[5];

  char* w = (char*)d_ws;
  auto alloc = [&](size_t bytes){ char* p = w; w += (bytes + 255) & ~(size_t)255; return p; };
  unsigned short* xb   = (unsigned short*)alloc((size_t)SL * HID * 2);
  unsigned short* wqkv = (unsigned short*)alloc((size_t)QKVN * HID * 2);
  unsigned short* owb  = (unsigned short*)alloc((size_t)HID * HID * 2);
  unsigned short* qkv  = (unsigned short*)alloc((size_t)SL * QKVN * 2);
  unsigned short* vt   = (unsigned short*)alloc((size_t)SL * KVW * 2);
  unsigned short* ab   = (unsigned short*)alloc((size_t)SL * HID * 2);
  float2*         tab  = (float2*)alloc((size_t)SL * 64 * sizeof(float2));

  auto cast = [&](const float* s, unsigned short* d, long n){
    int n8 = (int)(n / 8);
    int blocks = (n8 + 255) / 256; if (blocks > 2048) blocks = 2048;
    cast_f32_bf16<<<blocks, 256, 0, stream>>>(s, (uint4*)d, n8);
  };
  cast(hs, xb, (long)SL * HID);
  cast(qw, wqkv,                              (long)HID * HID);
  cast(kw, wqkv + (size_t)HID * HID,          (long)KVW * HID);
  cast(vw, wqkv + (size_t)(HID + KVW) * HID,  (long)KVW * HID);
  cast(ow, owb,                               (long)HID * HID);

  rope_table_kernel<<<(SL * 64 + 255) / 256, 256, 0, stream>>>(pos, tab);

  // fused QKV projection: [2048][6144] = xb [2048][4096] @ wqkv[6144][4096]^T
  gemm_bt<false><<<dim3(QKVN / 128, SL / 128), 256, 0, stream>>>(xb, wqkv, qkv, SL, QKVN, HID);

  rope_apply_kernel<<<(SL * NH  * 64 + 255) / 256, 256, 0, stream>>>(qkv,        tab, NH,  QKVN);
  rope_apply_kernel<<<(SL * NKV * 64 + 255) / 256, 256, 0, stream>>>(qkv + HID,  tab, NKV, QKVN);

  transpose_v_kernel<<<dim3(SL / 64, HD / 64, NKV), 256, 0, stream>>>(qkv + HID + KVW, QKVN, vt);

  // grid: 8 KV groups x 64 q-blocks of 32 rows
  flash_attn_kernel<<<dim3(NKV, SL / 32), 512, 0, stream>>>(qkv, qkv + HID, vt, ab);

  gemm_bt<true><<<dim3(HID / 128, SL / 128), 256, 0, stream>>>(ab, owb, d_out, SL, HID, HID);
}

// Round 5
// 366.493 us; speedup vs baseline: 1.8097x; 1.1346x over previous
//
#include <hip/hip_runtime.h>
#include <hip/hip_bf16.h>

#define NH   32
#define NKV  8
#define HD   128
#define SL   2048
#define HID  4096
#define KVW  1024   // NKV*HD
#define QKVN 6144   // HID + 2*KVW

typedef __attribute__((ext_vector_type(8))) short short8;
typedef __attribute__((ext_vector_type(4))) float f32x4;

static __device__ __forceinline__ unsigned short f2bf(float f){
  union { float f; unsigned int i; } v; v.f = f;
  unsigned int r = v.i + 0x7FFFu + ((v.i >> 16) & 1u);
  return (unsigned short)(r >> 16);
}
static __device__ __forceinline__ float bf2f(unsigned short u){
  union { unsigned int i; float f; } v; v.i = ((unsigned int)u) << 16; return v.f;
}
static __device__ __forceinline__ unsigned int pack2(float lo, float hi){
  return (unsigned int)f2bf(lo) | ((unsigned int)f2bf(hi) << 16);
}
static __device__ __forceinline__ unsigned int cvtpk(float lo, float hi){
  unsigned int d;
  asm("v_cvt_pk_bf16_f32 %0, %1, %2" : "=v"(d) : "v"(lo), "v"(hi));
  return d;
}

// async global -> LDS, 16 B per lane. LDS dest is wave-uniform base + lane*16.
static __device__ __forceinline__ void gload_lds16(const void* g, void* l){
  __builtin_amdgcn_global_load_lds(
      (const __attribute__((address_space(1))) void*)g,
      (__attribute__((address_space(3))) void*)l,
      16, 0, 0);
}

// ---------------- cast fp32 -> bf16, 8 elems/thread ----------------
__global__ void cast_f32_bf16(const float* __restrict__ src, uint4* __restrict__ dst, int n8){
  int stride = gridDim.x * blockDim.x;
  for (int i = blockIdx.x * blockDim.x + threadIdx.x; i < n8; i += stride){
    float4 a = ((const float4*)src)[2*i + 0];
    float4 b = ((const float4*)src)[2*i + 1];
    uint4 o;
    o.x = pack2(a.x, a.y); o.y = pack2(a.z, a.w);
    o.z = pack2(b.x, b.y); o.w = pack2(b.z, b.w);
    dst[i] = o;
  }
}

// ---------------- RoPE cos/sin table ----------------
__global__ void rope_table_kernel(const int* __restrict__ pos, float2* __restrict__ tab){
  int i = blockIdx.x * blockDim.x + threadIdx.x;
  if (i >= SL * 64) return;
  int s = i >> 6, f = i & 63;
  float inv = expf(-((float)(2 * f) / 128.0f) * 9.210340371976184f);
  float ang = (float)pos[s] * inv;
  float sn, cs;
  sincosf(ang, &sn, &cs);
  tab[i] = make_float2(cs, sn);
}

// ---------------- in-place RoPE on bf16 [s][stride] ----------------
__global__ void rope_apply_kernel(unsigned short* x, const float2* __restrict__ tab,
                                  int nheads, int rowstride){
  int i = blockIdx.x * blockDim.x + threadIdx.x;
  int total = SL * nheads * 64;
  if (i >= total) return;
  int f = i & 63;
  int t = i >> 6;
  int h = t % nheads;
  int s = t / nheads;
  float2 cs = tab[s * 64 + f];
  size_t base = (size_t)s * rowstride + h * HD;
  float x1 = bf2f(x[base + f]);
  float x2 = bf2f(x[base + f + 64]);
  x[base + f]      = f2bf(x1 * cs.x - x2 * cs.y);
  x[base + f + 64] = f2bf(x2 * cs.x + x1 * cs.y);
}

// ========== bt-GEMM: C[M][N] = A[M][K] * B[N][K]^T ==========
// 128x128 tile, BK=32, 4 waves (2x2), gload_lds staging, double-buffered,
// one barrier per K-step. 2D-rectangle XCD swizzle.
template<bool F32OUT>
__global__ __launch_bounds__(256) void gemm_bt(
  const unsigned short* __restrict__ A,
  const unsigned short* __restrict__ B,
  void* __restrict__ Cp, int M, int N, int K)
{
  __shared__ __align__(16) unsigned short As[2][128 * 32];
  __shared__ __align__(16) unsigned short Bs[2][128 * 32];
  const int tid = threadIdx.x;
  const int lane = tid & 63, wid = tid >> 6;
  const int g = lane >> 4, c15 = lane & 15;
  const int wr = wid >> 1, wc = wid & 1;

  // ---- 2D rect XCD swizzle ----
  const int gx = gridDim.x, gy = gridDim.y;
  const int nwg = gx * gy;
  const int lin = blockIdx.y * gx + blockIdx.x;
  int mb, nb;
  const int cpx = nwg >> 3;            // blocks per XCD
  const int RN  = cpx >> 3;            // rect = 8(m) x RN(n)
  if (RN > 0 && (gy & 7) == 0 && (cpx & 7) == 0 && gx % RN == 0 && (8 % (gx / RN)) == 0){
    int xcd = lin & 7, j = lin >> 3;
    int nrc = gx / RN;                 // rect columns across chip
    int rr = xcd / nrc, rc = xcd % nrc;
    mb = rr * 8 + (j & 7);             // m-major within rect
    nb = rc * RN + (j >> 3);
  } else {
    mb = lin / gx; nb = lin % gx;
  }
  const int m0 = mb * 128, n0 = nb * 128;

  const int srow = wid * 32 + (lane >> 2);
  const int scol = (lane & 3) * 8;
  const unsigned short* Ag = &A[(size_t)(m0 + srow) * K + scol];
  const unsigned short* Bg = &B[(size_t)(n0 + srow) * K + scol];
  const size_t K16 = (size_t)16 * K;

  f32x4 acc[4][4] = {};

  gload_lds16(Ag,       &As[0][wid * 1024]);
  gload_lds16(Ag + K16, &As[0][wid * 1024 + 512]);
  gload_lds16(Bg,       &Bs[0][wid * 1024]);
  gload_lds16(Bg + K16, &Bs[0][wid * 1024 + 512]);
  __syncthreads();

  const int nk = K >> 5;
  for (int t = 0; t < nk; ++t){
    const int cur = t & 1;
    if (t + 1 < nk){
      const unsigned short* a2 = Ag + (size_t)(t + 1) * 32;
      const unsigned short* b2 = Bg + (size_t)(t + 1) * 32;
      const int nb2 = cur ^ 1;
      gload_lds16(a2,       &As[nb2][wid * 1024]);
      gload_lds16(a2 + K16, &As[nb2][wid * 1024 + 512]);
      gload_lds16(b2,       &Bs[nb2][wid * 1024]);
      gload_lds16(b2 + K16, &Bs[nb2][wid * 1024 + 512]);
    }
    short8 af[4], bfr[4];
#pragma unroll
    for (int m = 0; m < 4; ++m)
      af[m] = *(const short8*)(&As[cur][(wr * 64 + m * 16 + c15) * 32 + g * 8]);
#pragma unroll
    for (int n = 0; n < 4; ++n)
      bfr[n] = *(const short8*)(&Bs[cur][(wc * 64 + n * 16 + c15) * 32 + g * 8]);
#pragma unroll
    for (int m = 0; m < 4; ++m)
#pragma unroll
      for (int n = 0; n < 4; ++n)
        acc[m][n] = __builtin_amdgcn_mfma_f32_16x16x32_bf16(af[m], bfr[n], acc[m][n], 0, 0, 0);
    __syncthreads();
  }

#pragma unroll
  for (int m = 0; m < 4; ++m)
#pragma unroll
    for (int n = 0; n < 4; ++n){
      int row = m0 + wr * 64 + m * 16 + g * 4;
      int col = n0 + wc * 64 + n * 16 + c15;
      f32x4 v = acc[m][n];
      if (F32OUT){
        float* C = (float*)Cp;
#pragma unroll
        for (int r = 0; r < 4; ++r) C[(size_t)(row + r) * N + col] = v[r];
      } else {
        unsigned short* C = (unsigned short*)Cp;
#pragma unroll
        for (int r = 0; r < 4; ++r) C[(size_t)(row + r) * N + col] = f2bf(v[r]);
      }
    }
}

// ---------------- V transpose: v[s][h*128+d] (stride vstride) -> vt[h][d][s] ----------------
__global__ void transpose_v_kernel(const unsigned short* __restrict__ v, int vstride,
                                   unsigned short* __restrict__ vt){
  __shared__ unsigned short t[64][65];
  int h  = blockIdx.z;
  int d0 = blockIdx.y * 64;
  int s0 = blockIdx.x * 64;
  int c  = threadIdx.x & 63;
  int r0 = threadIdx.x >> 6;
#pragma unroll
  for (int r = r0; r < 64; r += 4) t[r][c] = v[(size_t)(s0 + r) * vstride + h * HD + d0 + c];
  __syncthreads();
#pragma unroll
  for (int r = r0; r < 64; r += 4) vt[(size_t)(h * HD + d0 + r) * SL + s0 + c] = t[c][r];
}

// ---------------- flash attention: swapped-QK in-register softmax ----------------
// block = 512 thr (8 waves) = 4 q-heads of one KV group x 2 row-groups of 16 rows.
// Swapped QK: sc = mfma(K_frag, Q_frag) -> lane&15 = q, rows = kv. Softmax per-lane
// (2 shfl_xor for max, 2 for sum). P stays in regs: cvt_pk -> bf16 dwords, 4-lane
// group shfl redistribution into the PV A-frag. T14: K/V global->reg loads issued
// early, ds_write next iter. T13 defer-max THR=8.
__global__ __launch_bounds__(512, 4) void flash_attn_kernel(
  const unsigned short* __restrict__ Q,    // row stride QKVN
  const unsigned short* __restrict__ Kb,   // row stride QKVN
  const unsigned short* __restrict__ Vt,   // [kvh*128+d][SL]
  unsigned short* __restrict__ O)          // row stride HID
{
  __shared__ __align__(16) unsigned short Ks[64 * 128];    // stride 256 B, XOR-swizzled
  __shared__ __align__(16) unsigned short Vs[128 * 64];    // stride 128 B, XOR-swizzled
  const int tid = threadIdx.x, lane = tid & 63, wid = tid >> 6;
  const int g = lane >> 4, c15 = lane & 15;
  const int kvh = blockIdx.x;
  const int yy = blockIdx.y;
  const int qb = (yy & 1) ? (yy >> 1) : (63 - (yy >> 1));   // heavy/light interleave
  const int h = kvh * 4 + (wid & 3);
  const int rg = wid >> 2;
  const int q0 = qb * 32;
  const int qg = q0 + rg * 16 + c15;       // this lane's q row

  // Q fragments (B-operand): col=c15 -> q, k = kk*32 + g*8 + j
  short8 aq[4];
  {
    size_t qrow = (size_t)qg * QKVN + h * HD;
#pragma unroll
    for (int kk = 0; kk < 4; ++kk)
      aq[kk] = *(const short8*)(&Q[qrow + kk * 32 + g * 8]);
  }

  // staging mapping: K 64 rows x 8 thr/row x 2 chunks; V 128 rows x 4 thr/row x 2
  const int krow = tid >> 3, kcol = (tid & 7) * 8;
  const int vrow = tid >> 2, vcol = (tid & 3) * 8;
  const unsigned short* Kgb = Kb + (size_t)kvh * HD;
  const unsigned short* Vgb = Vt + ((size_t)kvh * HD + vrow) * SL;

  uint4 kr0, kr1, vr0, vr1;
  {
    const unsigned short* kg = Kgb + (size_t)krow * QKVN + kcol;
    kr0 = *(const uint4*)kg; kr1 = *(const uint4*)(kg + 64);
    const unsigned short* vg = Vgb + vcol;
    vr0 = *(const uint4*)vg; vr1 = *(const uint4*)(vg + 32);
  }

  float m_i = -1e30f, l_i = 0.f;
  f32x4 oacc[8];
#pragma unroll
  for (int df = 0; df < 8; ++df) oacc[df] = (f32x4){0.f, 0.f, 0.f, 0.f};

  const float scl2 = 0.08838834764831845f * 1.4426950408889634f;  // 1/sqrt(128)*log2e
  const int nt = (q0 + 31) / 64 + 1;
  for (int kt = 0; kt < nt; ++kt){
    // publish staged tile (regs loaded last iter / prologue)
    *(uint4*)((char*)Ks + krow * 256 + (( kcol * 2       ) ^ ((krow & 7) << 4))) = kr0;
    *(uint4*)((char*)Ks + krow * 256 + (((kcol * 2) + 128) ^ ((krow & 7) << 4))) = kr1;
    *(uint4*)((char*)Vs + vrow * 128 + (( vcol * 2       ) ^ ((vrow & 7) << 4))) = vr0;
    *(uint4*)((char*)Vs + vrow * 128 + (((vcol * 2) +  64) ^ ((vrow & 7) << 4))) = vr1;
    __syncthreads();

    // issue next tile's global loads (latency hides under compute)
    if (kt + 1 < nt){
      const unsigned short* kg = Kgb + (size_t)((kt + 1) * 64 + krow) * QKVN + kcol;
      kr0 = *(const uint4*)kg; kr1 = *(const uint4*)(kg + 64);
      const unsigned short* vg = Vgb + (kt + 1) * 64 + vcol;
      vr0 = *(const uint4*)vg; vr1 = *(const uint4*)(vg + 32);
    }

    // S^T = K Q : lane holds q=c15, kv = f*16 + g*4 + r
    f32x4 sc[4];
    __builtin_amdgcn_s_setprio(1);
#pragma unroll
    for (int f = 0; f < 4; ++f){
      sc[f] = (f32x4){0.f, 0.f, 0.f, 0.f};
#pragma unroll
      for (int kk = 0; kk < 4; ++kk){
        short8 bk = *(const short8*)((const char*)Ks + (f * 16 + c15) * 256 +
                                     ((kk * 64 + g * 16) ^ ((c15 & 7) << 4)));
        sc[f] = __builtin_amdgcn_mfma_f32_16x16x32_bf16(bk, aq[kk], sc[f], 0, 0, 0);
      }
    }
    __builtin_amdgcn_s_setprio(0);

    // mask + scale (exp2 domain)
    float p[4][4];
#pragma unroll
    for (int f = 0; f < 4; ++f)
#pragma unroll
      for (int r = 0; r < 4; ++r){
        int kvg = kt * 64 + f * 16 + g * 4 + r;
        p[f][r] = (kvg <= qg) ? sc[f][r] * scl2 : -1e30f;
      }

    // per-lane max + 2-shfl group reduce
    float pmax = p[0][0];
#pragma unroll
    for (int f = 0; f < 4; ++f)
#pragma unroll
      for (int r = 0; r < 4; ++r) pmax = fmaxf(pmax, p[f][r]);
    pmax = fmaxf(pmax, __shfl_xor(pmax, 16, 64));
    pmax = fmaxf(pmax, __shfl_xor(pmax, 32, 64));

    // defer-max: skip rescale when growth small
    if (!__all(pmax - m_i <= 8.0f)){
      float mnew = fmaxf(m_i, pmax);
      float cf = exp2f(m_i - mnew);
      float cfr[4];
#pragma unroll
      for (int r = 0; r < 4; ++r) cfr[r] = __shfl(cf, (lane & 48) | (g * 4 + r), 64);
#pragma unroll
      for (int df = 0; df < 8; ++df)
#pragma unroll
        for (int r = 0; r < 4; ++r) oacc[df][r] *= cfr[r];
      l_i *= cf;
      m_i = mnew;
    }

    float lsum = 0.f;
#pragma unroll
    for (int f = 0; f < 4; ++f)
#pragma unroll
      for (int r = 0; r < 4; ++r){ float e = exp2f(p[f][r] - m_i); p[f][r] = e; lsum += e; }
    lsum += __shfl_xor(lsum, 16, 64);
    lsum += __shfl_xor(lsum, 32, 64);
    l_i += lsum;

    // pack P -> bf16 dwords: pd[f][pr] = (p[f][2pr], p[f][2pr+1])
    unsigned int pd[4][2];
#pragma unroll
    for (int f = 0; f < 4; ++f){
      pd[f][0] = cvtpk(p[f][0], p[f][1]);
      pd[f][1] = cvtpk(p[f][2], p[f][3]);
    }

    // PV: redistribute P into A-frag via 4-lane-group shuffles, then MFMA
    const int src0 = ((g & 1) << 5) | c15;
    const int src1 = src0 + 16;
    const bool hiF = (g >= 2);
#pragma unroll
    for (int kk = 0; kk < 2; ++kk){
      union { unsigned int u[4]; short8 s8; } pa;
#pragma unroll
      for (int pr = 0; pr < 2; ++pr){
        unsigned int a0 = __shfl((int)pd[2 * kk + 0][pr], src0, 64);
        unsigned int b0 = __shfl((int)pd[2 * kk + 1][pr], src0, 64);
        unsigned int a1 = __shfl((int)pd[2 * kk + 0][pr], src1, 64);
        unsigned int b1 = __shfl((int)pd[2 * kk + 1][pr], src1, 64);
        pa.u[pr]     = hiF ? b0 : a0;
        pa.u[2 + pr] = hiF ? b1 : a1;
      }
      __builtin_amdgcn_s_setprio(1);
#pragma unroll
      for (int df = 0; df < 8; ++df){
        short8 bv = *(const short8*)((const char*)Vs + (df * 16 + c15) * 128 +
                                     ((kk * 64 + g * 16) ^ ((c15 & 7) << 4)));
        oacc[df] = __builtin_amdgcn_mfma_f32_16x16x32_bf16(pa.s8, bv, oacc[df], 0, 0, 0);
      }
      __builtin_amdgcn_s_setprio(0);
    }
    __syncthreads();   // everyone done reading Ks/Vs before next publish
  }

  // final: divide by l (per output row) and store
  float lr[4];
#pragma unroll
  for (int r = 0; r < 4; ++r) lr[r] = __shfl(l_i, (lane & 48) | (g * 4 + r), 64);
#pragma unroll
  for (int df = 0; df < 8; ++df)
#pragma unroll
    for (int r = 0; r < 4; ++r){
      int row = q0 + rg * 16 + g * 4 + r;
      O[(size_t)row * HID + h * HD + df * 16 + c15] = f2bf(oacc[df][r] / lr[r]);
    }
}

extern "C" void kernel_launch(void* const* d_in, const int* in_sizes, int n_in,
                              void* d_out, int out_size, void* d_ws, size_t ws_size,
                              hipStream_t stream)
{
  const float* hs  = (const float*)d_in[0];
  const float* qw  = (const float*)d_in[1];
  const float* kw  = (const float*)d_in[2];
  const float* vw  = (const float*)d_in[3];
  const float* ow  = (const float*)d_in[4];
  const int*   pos = (const int*)d_in[5];

  char* w = (char*)d_ws;
  auto alloc = [&](size_t bytes){ char* p = w; w += (bytes + 255) & ~(size_t)255; return p; };
  unsigned short* xb   = (unsigned short*)alloc((size_t)SL * HID * 2);
  unsigned short* wqkv = (unsigned short*)alloc((size_t)QKVN * HID * 2);
  unsigned short* owb  = (unsigned short*)alloc((size_t)HID * HID * 2);
  unsigned short* qkv  = (unsigned short*)alloc((size_t)SL * QKVN * 2);
  unsigned short* vt   = (unsigned short*)alloc((size_t)SL * KVW * 2);
  unsigned short* ab   = (unsigned short*)alloc((size_t)SL * HID * 2);
  float2*         tab  = (float2*)alloc((size_t)SL * 64 * sizeof(float2));

  auto cast = [&](const float* s, unsigned short* d, long n){
    int n8 = (int)(n / 8);
    int blocks = (n8 + 255) / 256; if (blocks > 2048) blocks = 2048;
    cast_f32_bf16<<<blocks, 256, 0, stream>>>(s, (uint4*)d, n8);
  };
  cast(hs, xb, (long)SL * HID);
  cast(qw, wqkv,                              (long)HID * HID);
  cast(kw, wqkv + (size_t)HID * HID,          (long)KVW * HID);
  cast(vw, wqkv + (size_t)(HID + KVW) * HID,  (long)KVW * HID);
  cast(ow, owb,                               (long)HID * HID);

  rope_table_kernel<<<(SL * 64 + 255) / 256, 256, 0, stream>>>(pos, tab);

  // fused QKV projection: [2048][6144] = xb [2048][4096] @ wqkv[6144][4096]^T
  gemm_bt<false><<<dim3(QKVN / 128, SL / 128), 256, 0, stream>>>(xb, wqkv, qkv, SL, QKVN, HID);

  rope_apply_kernel<<<(SL * NH  * 64 + 255) / 256, 256, 0, stream>>>(qkv,        tab, NH,  QKVN);
  rope_apply_kernel<<<(SL * NKV * 64 + 255) / 256, 256, 0, stream>>>(qkv + HID,  tab, NKV, QKVN);

  transpose_v_kernel<<<dim3(SL / 64, HD / 64, NKV), 256, 0, stream>>>(qkv + HID + KVW, QKVN, vt);

  // grid: 8 KV groups x 64 q-blocks of 32 rows
  flash_attn_kernel<<<dim3(NKV, SL / 32), 512, 0, stream>>>(qkv, qkv + HID, vt, ab);

  gemm_bt<true><<<dim3(HID / 128, SL / 128), 256, 0, stream>>>(ab, owb, d_out, SL, HID, HID);
}